// Round 1
// baseline (699.671 us; speedup 1.0000x reference)
//
#include <hip/hip_runtime.h>

// Problem constants
#define DM   1024      // d_model
#define NH   16        // heads
#define DH   64        // depth per head
#define BATCH 2
#define SEQ  1024      // effective rows after slicing

// ---------------------------------------------------------------------------
// Generic f32 tiled GEMM body: C[BMxBN] = A[BMxK] * W[KxBN] (+bias)
// BM=128 fixed, BK=16, 256 threads, micro-tile TM=8 x TN.
// All dims assumed multiples of tiles (true for this problem).
// ---------------------------------------------------------------------------
template<int BN, int TN>
__device__ __forceinline__ void gemm_body(
    const float* __restrict__ A, int lda,
    const float* __restrict__ W, int ldw,
    const float* __restrict__ bias,
    float* __restrict__ C, int ldc, int K)
{
  constexpr int BM = 128, BK = 16, TM = 8;
  static_assert((BM / TM) * (BN / TN) == 256, "256 threads");
  __shared__ float As[BK][BM];   // transposed A tile: As[k][m]
  __shared__ float Ws[BK][BN];   // Ws[k][n]

  const int tid = threadIdx.x;
  const int tx  = tid & 15;      // n-direction, 0..15
  const int ty  = tid >> 4;      // m-direction, 0..15
  const int row0 = blockIdx.y * BM;
  const int col0 = blockIdx.x * BN;

  float acc[TM][TN];
#pragma unroll
  for (int i = 0; i < TM; i++)
#pragma unroll
    for (int j = 0; j < TN; j++) acc[i][j] = 0.f;

  const int ar = tid >> 1;          // 0..127
  const int ac = (tid & 1) * 8;     // 0 or 8

  for (int k0 = 0; k0 < K; k0 += BK) {
    // --- A tile: BM x BK, store transposed ---
    {
      const float* ap = A + (long)(row0 + ar) * lda + (k0 + ac);
      float4 v0 = *(const float4*)ap;
      float4 v1 = *(const float4*)(ap + 4);
      As[ac + 0][ar] = v0.x; As[ac + 1][ar] = v0.y;
      As[ac + 2][ar] = v0.z; As[ac + 3][ar] = v0.w;
      As[ac + 4][ar] = v1.x; As[ac + 5][ar] = v1.y;
      As[ac + 6][ar] = v1.z; As[ac + 7][ar] = v1.w;
    }
    // --- W tile: BK x BN ---
    {
      constexpr int PER = BK * BN / 256;   // 8 (BN=128) or 4 (BN=64)
      const int wr = (tid * PER) / BN;
      const int wc = (tid * PER) % BN;
      const float* wp = W + (long)(k0 + wr) * ldw + col0 + wc;
      if constexpr (PER == 8) {
        *(float4*)&Ws[wr][wc]     = *(const float4*)wp;
        *(float4*)&Ws[wr][wc + 4] = *(const float4*)(wp + 4);
      } else {
        *(float4*)&Ws[wr][wc]     = *(const float4*)wp;
      }
    }
    __syncthreads();
#pragma unroll
    for (int kk = 0; kk < BK; kk++) {
      float a[TM], w[TN];
#pragma unroll
      for (int i = 0; i < TM; i++) a[i] = As[kk][ty * TM + i];
#pragma unroll
      for (int j = 0; j < TN; j++) w[j] = Ws[kk][tx * TN + j];
#pragma unroll
      for (int i = 0; i < TM; i++)
#pragma unroll
        for (int j = 0; j < TN; j++)
          acc[i][j] = fmaf(a[i], w[j], acc[i][j]);
    }
    __syncthreads();
  }

#pragma unroll
  for (int i = 0; i < TM; i++) {
    const int r = row0 + ty * TM + i;
    float* cp = C + (long)r * ldc + col0 + tx * TN;
#pragma unroll
    for (int j = 0; j < TN; j += 4) {
      float4 v;
      v.x = acc[i][j + 0]; v.y = acc[i][j + 1];
      v.z = acc[i][j + 2]; v.w = acc[i][j + 3];
      if (bias) {
        const float* bp = bias + col0 + tx * TN + j;
        v.x += bp[0]; v.y += bp[1]; v.z += bp[2]; v.w += bp[3];
      }
      *(float4*)(cp + j) = v;
    }
  }
}

// ---------------------------------------------------------------------------
// Fused QKV projection: grid.z = 6 -> (src 0..2) x (batch 0..1)
// ---------------------------------------------------------------------------
struct ProjArgs {
  const float* A[3];
  const float* W[3];
  const float* bias[3];
  float* C[3];
  long az[3];
};

__global__ __launch_bounds__(256) void proj_kernel(ProjArgs p) {
  const int z   = blockIdx.z;
  const int sel = z >> 1;   // 0:q 1:k 2:v
  const int b   = z & 1;
  const float* A = p.A[sel] + (long)b * p.az[sel];
  float* C = p.C[sel] + (long)b * (long)SEQ * DM;
  gemm_body<128, 8>(A, DM, p.W[sel], DM, p.bias[sel], C, DM, DM);
}

// ---------------------------------------------------------------------------
// Scores: per (b,h): S = Qh * Kh^T, epilogue relu(S/8) + mask*-1e9,
// written straight into the att_weights output region.
// ---------------------------------------------------------------------------
__device__ __forceinline__ float score_ep(float a, int m) {
  float s = fmaxf(a * 0.125f, 0.f);
  return m ? (s - 1e9f) : s;
}

__global__ __launch_bounds__(256) void scores_kernel(
    const float* __restrict__ qq, const float* __restrict__ kk,
    const int* __restrict__ mask, float* __restrict__ attw)
{
  const int z = blockIdx.z;           // b*16 + h
  const int b = z >> 4, h = z & 15;
  const float* Aq = qq + (long)b * (SEQ * DM) + h * DH;   // row s: +s*DM
  const float* Bk = kk + (long)b * (SEQ * DM) + h * DH;   // row t: +t*DM
  const int*   mk = mask + (long)b * (SEQ * SEQ);
  float* out = attw + (long)z * (SEQ * SEQ);

  constexpr int BM = 128, BN = 128, BK = 16, TM = 8, TN = 8;
  __shared__ float Qs[BK][BM];
  __shared__ float Ks[BK][BN];
  const int tid = threadIdx.x, tx = tid & 15, ty = tid >> 4;
  const int row0 = blockIdx.y * BM, col0 = blockIdx.x * BN;

  float acc[TM][TN];
#pragma unroll
  for (int i = 0; i < TM; i++)
#pragma unroll
    for (int j = 0; j < TN; j++) acc[i][j] = 0.f;

  const int ar = tid >> 1;
  const int ac = (tid & 1) * 8;

  for (int k0 = 0; k0 < DH; k0 += BK) {
    {
      const float* ap = Aq + (long)(row0 + ar) * DM + k0 + ac;
      float4 v0 = *(const float4*)ap;
      float4 v1 = *(const float4*)(ap + 4);
      Qs[ac + 0][ar] = v0.x; Qs[ac + 1][ar] = v0.y;
      Qs[ac + 2][ar] = v0.z; Qs[ac + 3][ar] = v0.w;
      Qs[ac + 4][ar] = v1.x; Qs[ac + 5][ar] = v1.y;
      Qs[ac + 6][ar] = v1.z; Qs[ac + 7][ar] = v1.w;
    }
    {
      const float* bp = Bk + (long)(col0 + ar) * DM + k0 + ac;
      float4 v0 = *(const float4*)bp;
      float4 v1 = *(const float4*)(bp + 4);
      Ks[ac + 0][ar] = v0.x; Ks[ac + 1][ar] = v0.y;
      Ks[ac + 2][ar] = v0.z; Ks[ac + 3][ar] = v0.w;
      Ks[ac + 4][ar] = v1.x; Ks[ac + 5][ar] = v1.y;
      Ks[ac + 6][ar] = v1.z; Ks[ac + 7][ar] = v1.w;
    }
    __syncthreads();
#pragma unroll
    for (int kk2 = 0; kk2 < BK; kk2++) {
      float a[TM], w[TN];
#pragma unroll
      for (int i = 0; i < TM; i++) a[i] = Qs[kk2][ty * TM + i];
#pragma unroll
      for (int j = 0; j < TN; j++) w[j] = Ks[kk2][tx * TN + j];
#pragma unroll
      for (int i = 0; i < TM; i++)
#pragma unroll
        for (int j = 0; j < TN; j++)
          acc[i][j] = fmaf(a[i], w[j], acc[i][j]);
    }
    __syncthreads();
  }

#pragma unroll
  for (int i = 0; i < TM; i++) {
    const int r = row0 + ty * TM + i;
    const int c = col0 + tx * TN;
    const int4* mp = (const int4*)(mk + (long)r * SEQ + c);
    int4 m0 = mp[0], m1 = mp[1];
    float4 v0, v1;
    v0.x = score_ep(acc[i][0], m0.x); v0.y = score_ep(acc[i][1], m0.y);
    v0.z = score_ep(acc[i][2], m0.z); v0.w = score_ep(acc[i][3], m0.w);
    v1.x = score_ep(acc[i][4], m1.x); v1.y = score_ep(acc[i][5], m1.y);
    v1.z = score_ep(acc[i][6], m1.z); v1.w = score_ep(acc[i][7], m1.w);
    float* op = out + (long)r * SEQ + c;
    *(float4*)op       = v0;
    *(float4*)(op + 4) = v1;
  }
}

// ---------------------------------------------------------------------------
// In-place row softmax on the att region. 1 block (256 thr) per row of 1024.
// ---------------------------------------------------------------------------
__global__ __launch_bounds__(256) void softmax_kernel(float* __restrict__ attw)
{
  const long g = blockIdx.x;               // 0 .. B*NH*SEQ-1
  float* row = attw + g * SEQ;
  const int tid = threadIdx.x;
  float4 v = *(float4*)(row + tid * 4);

  float m = fmaxf(fmaxf(v.x, v.y), fmaxf(v.z, v.w));
#pragma unroll
  for (int o = 32; o >= 1; o >>= 1) m = fmaxf(m, __shfl_xor(m, o, 64));
  __shared__ float redm[4];
  const int wave = tid >> 6, lane = tid & 63;
  if (lane == 0) redm[wave] = m;
  __syncthreads();
  m = fmaxf(fmaxf(redm[0], redm[1]), fmaxf(redm[2], redm[3]));

  v.x = __expf(v.x - m); v.y = __expf(v.y - m);
  v.z = __expf(v.z - m); v.w = __expf(v.w - m);
  float s = v.x + v.y + v.z + v.w;
#pragma unroll
  for (int o = 32; o >= 1; o >>= 1) s += __shfl_xor(s, o, 64);
  __shared__ float reds[4];
  if (lane == 0) reds[wave] = s;
  __syncthreads();
  s = reds[0] + reds[1] + reds[2] + reds[3];

  const float inv = 1.0f / s;
  v.x *= inv; v.y *= inv; v.z *= inv; v.w *= inv;
  *(float4*)(row + tid * 4) = v;
}

// ---------------------------------------------------------------------------
// PV: per (b,h): out_hs[b, s, h*64+d] = sum_t att[b,h,s,t] * vv[b,t,h*64+d]
// ---------------------------------------------------------------------------
__global__ __launch_bounds__(256) void pv_kernel(
    const float* __restrict__ attw, const float* __restrict__ vv,
    float* __restrict__ out_hs)
{
  const int z = blockIdx.z, b = z >> 4, h = z & 15;
  gemm_body<64, 4>(attw + (long)z * (SEQ * SEQ), SEQ,
                   vv + (long)b * (SEQ * DM) + h * DH, DM,
                   nullptr,
                   out_hs + (long)b * (SEQ * DM) + h * DH, DM, SEQ);
}

// ---------------------------------------------------------------------------
// Final: output = out_hs @ Wo + bo
// ---------------------------------------------------------------------------
__global__ __launch_bounds__(256) void out_kernel(
    const float* __restrict__ A, const float* __restrict__ Wo,
    const float* __restrict__ bo, float* __restrict__ C)
{
  const int b = blockIdx.z;
  gemm_body<128, 8>(A + (long)b * (SEQ * DM), DM, Wo, DM, bo,
                    C + (long)b * (SEQ * DM), DM, DM);
}

// ---------------------------------------------------------------------------
extern "C" void kernel_launch(void* const* d_in, const int* in_sizes, int n_in,
                              void* d_out, int out_size, void* d_ws, size_t ws_size,
                              hipStream_t stream)
{
  const float* v    = (const float*)d_in[0];
  const float* k    = (const float*)d_in[1];
  const float* q    = (const float*)d_in[2];
  const int*   mask = (const int*)  d_in[3];
  const float* Wq   = (const float*)d_in[4];
  const float* bq   = (const float*)d_in[5];
  const float* Wk   = (const float*)d_in[6];
  const float* bk   = (const float*)d_in[7];
  const float* Wv   = (const float*)d_in[8];
  const float* bv   = (const float*)d_in[9];
  const float* Wo   = (const float*)d_in[10];
  const float* bo   = (const float*)d_in[11];

  // workspace layout (f32 elements): qq | kk | vv | out_hs  (32 MB total)
  float* qq  = (float*)d_ws;
  float* kkp = qq  + (long)BATCH * SEQ * DM;
  float* vvp = kkp + (long)BATCH * SEQ * DM;
  float* ohs = vvp + (long)BATCH * SEQ * DM;

  float* out0 = (float*)d_out;                       // (B,1024,1024)
  float* attw = out0 + (long)BATCH * SEQ * DM;       // (B,16,1024,1024)

  ProjArgs p;
  p.A[0] = q + DM;  p.A[1] = k;   p.A[2] = v;        // q skips row 0
  p.W[0] = Wq;      p.W[1] = Wk;  p.W[2] = Wv;
  p.bias[0] = bq;   p.bias[1] = bk; p.bias[2] = bv;
  p.C[0] = qq;      p.C[1] = kkp; p.C[2] = vvp;
  p.az[0] = 1025L * DM; p.az[1] = 1025L * DM; p.az[2] = 1024L * DM;

  dim3 blk(256);
  hipLaunchKernelGGL(proj_kernel,   dim3(8, 8, 6),  blk, 0, stream, p);
  hipLaunchKernelGGL(scores_kernel, dim3(8, 8, 32), blk, 0, stream, qq, kkp, mask, attw);
  hipLaunchKernelGGL(softmax_kernel, dim3(BATCH * NH * SEQ), blk, 0, stream, attw);
  hipLaunchKernelGGL(pv_kernel,     dim3(1, 8, 32), blk, 0, stream, attw, vvp, ohs);
  hipLaunchKernelGGL(out_kernel,    dim3(8, 8, 2),  blk, 0, stream, ohs, Wo, bo, out0);
}

// Round 2
// 454.805 us; speedup vs baseline: 1.5384x; 1.5384x over previous
//
#include <hip/hip_runtime.h>

#define DM   1024
#define NH   16
#define DH   64
#define BATCH 2
#define SEQ  1024

typedef __attribute__((ext_vector_type(8))) short   short8;
typedef __attribute__((ext_vector_type(4))) float   f32x4;
typedef __attribute__((ext_vector_type(4))) unsigned short ushort4v;

// ---- bf16 helpers (RNE) ----
__device__ __forceinline__ unsigned short f2bf(float f) {
  unsigned int u = __float_as_uint(f);
  u += 0x7FFFu + ((u >> 16) & 1u);
  return (unsigned short)(u >> 16);
}
__device__ __forceinline__ float bf2f(unsigned short h) {
  return __uint_as_float(((unsigned int)h) << 16);
}

// ---------------------------------------------------------------------------
// Split-bf16 MFMA GEMM: C[M x N](f32) = A(f32)[M x K] * B + bias
// B supplied pre-split as bf16 hi/lo, TRANSPOSED: BT[n][k], ldb = K.
// BM=64, BN=128, BK=32, 256 threads = 4 waves (2m x 2n), wave tile 32x64.
// 3-term emulation: hi*hi + hi*lo + lo*hi  (error ~2^-17, ~f32 quality).
// LDS is frag-ordered: [frag][lane][8] so every ds_read_b128 is
// lane-contiguous (conflict-free).
// ---------------------------------------------------------------------------
__device__ __forceinline__ void mfma_gemm(
    const float* __restrict__ A, long lda,
    const unsigned short* __restrict__ BTh,
    const unsigned short* __restrict__ BTl, long ldb,
    const float* __restrict__ bias, float* __restrict__ C, long ldc,
    int K, int row0, int col0)
{
  __shared__ short Ah[4][64][8];   // 4 KB
  __shared__ short Al[4][64][8];
  __shared__ short Bh[8][64][8];   // 8 KB
  __shared__ short Bl[8][64][8];

  const int tid  = threadIdx.x;
  const int wave = tid >> 6, lane = tid & 63;
  const int wm = wave & 1, wn = wave >> 1;

  f32x4 acc[2][4];
#pragma unroll
  for (int i = 0; i < 2; i++)
#pragma unroll
    for (int j = 0; j < 4; j++) acc[i][j] = (f32x4){0.f, 0.f, 0.f, 0.f};

  // A staging: thread t -> row am, k-octet ako (8 consecutive k = one frag-lane)
  const int am    = tid >> 2;            // 0..63
  const int ako   = (tid & 3) * 8;       // 0,8,16,24
  const int afrag = am >> 4;
  const int alane = (am & 15) + (ako >> 3) * 16;
  // B staging: thread t -> col bn, k-half bkh (16 consecutive k = two frag-lanes)
  const int bn     = tid >> 1;           // 0..127
  const int bkh    = tid & 1;            // 0,1
  const int bfrag  = bn >> 4;
  const int blane0 = (bn & 15) + (bkh * 2) * 16;

  const float*          aptr  = A   + (long)(row0 + am) * lda + ako;
  const unsigned short* bhptr = BTh + (long)(col0 + bn) * ldb + bkh * 16;
  const unsigned short* blptr = BTl + (long)(col0 + bn) * ldb + bkh * 16;

  for (int k0 = 0; k0 < K; k0 += 32) {
    // ---- stage A (f32 -> hi/lo bf16 in-register) ----
    float4 v0 = *(const float4*)(aptr + k0);
    float4 v1 = *(const float4*)(aptr + k0 + 4);
    float f[8] = {v0.x, v0.y, v0.z, v0.w, v1.x, v1.y, v1.z, v1.w};
    short8 hv, lv;
#pragma unroll
    for (int i = 0; i < 8; i++) {
      unsigned short h = f2bf(f[i]);
      hv[i] = (short)h;
      lv[i] = (short)f2bf(f[i] - bf2f(h));
    }
    *(short8*)&Ah[afrag][alane][0] = hv;
    *(short8*)&Al[afrag][alane][0] = lv;
    // ---- stage B (already bf16 hi/lo, contiguous along k) ----
    short8 b0 = *(const short8*)(bhptr + k0);
    short8 b1 = *(const short8*)(bhptr + k0 + 8);
    short8 c0 = *(const short8*)(blptr + k0);
    short8 c1 = *(const short8*)(blptr + k0 + 8);
    *(short8*)&Bh[bfrag][blane0][0]      = b0;
    *(short8*)&Bh[bfrag][blane0 + 16][0] = b1;
    *(short8*)&Bl[bfrag][blane0][0]      = c0;
    *(short8*)&Bl[bfrag][blane0 + 16][0] = c1;
    __syncthreads();

    // ---- fragment reads (conflict-free b128) + 3-term MFMA ----
    short8 a_h[2], a_l[2], b_h[4], b_l[4];
#pragma unroll
    for (int fm = 0; fm < 2; fm++) {
      a_h[fm] = *(short8*)&Ah[wm * 2 + fm][lane][0];
      a_l[fm] = *(short8*)&Al[wm * 2 + fm][lane][0];
    }
#pragma unroll
    for (int fn = 0; fn < 4; fn++) {
      b_h[fn] = *(short8*)&Bh[wn * 4 + fn][lane][0];
      b_l[fn] = *(short8*)&Bl[wn * 4 + fn][lane][0];
    }
#pragma unroll
    for (int fm = 0; fm < 2; fm++)
#pragma unroll
      for (int fn = 0; fn < 4; fn++) {
        acc[fm][fn] = __builtin_amdgcn_mfma_f32_16x16x32_bf16(
            a_h[fm], b_h[fn], acc[fm][fn], 0, 0, 0);
        acc[fm][fn] = __builtin_amdgcn_mfma_f32_16x16x32_bf16(
            a_h[fm], b_l[fn], acc[fm][fn], 0, 0, 0);
        acc[fm][fn] = __builtin_amdgcn_mfma_f32_16x16x32_bf16(
            a_l[fm], b_h[fn], acc[fm][fn], 0, 0, 0);
      }
    __syncthreads();
  }

  // ---- epilogue: C/D layout col=lane&15, row=(lane>>4)*4+i ----
  const int erow = (lane >> 4) * 4;
  const int ecol = lane & 15;
#pragma unroll
  for (int fm = 0; fm < 2; fm++)
#pragma unroll
    for (int fn = 0; fn < 4; fn++) {
      const int r0 = row0 + wm * 32 + fm * 16 + erow;
      const int cc = col0 + wn * 64 + fn * 16 + ecol;
      const float b = bias ? bias[cc] : 0.f;
#pragma unroll
      for (int i = 0; i < 4; i++)
        C[(long)(r0 + i) * ldc + cc] = acc[fm][fn][i] + b;
    }
}

// ---------------------------------------------------------------------------
// Weight split+transpose: W[K][N] f32 -> TH/TL[N][K] bf16 hi/lo
// ---------------------------------------------------------------------------
struct SplitTArgs {
  const float* W[4];
  unsigned short* TH[4];
  unsigned short* TL[4];
};

__global__ __launch_bounds__(256) void splitT_kernel(SplitTArgs s) {
  const int w = blockIdx.z;
  const float* W = s.W[w];
  unsigned short* TH = s.TH[w];
  unsigned short* TL = s.TL[w];
  __shared__ float tile[32][33];
  const int t = threadIdx.x;
  const int k0 = blockIdx.y * 32, n0 = blockIdx.x * 32;
  {
    const int r = t >> 3, c = (t & 7) * 4;
    float4 v = *(const float4*)(W + (long)(k0 + r) * DM + n0 + c);
    tile[r][c] = v.x; tile[r][c + 1] = v.y;
    tile[r][c + 2] = v.z; tile[r][c + 3] = v.w;
  }
  __syncthreads();
  const int n = t >> 3, k = (t & 7) * 4;
  ushort4v h, l;
#pragma unroll
  for (int i = 0; i < 4; i++) {
    float f = tile[k + i][n];
    unsigned short hh = f2bf(f);
    h[i] = hh;
    l[i] = f2bf(f - bf2f(hh));
  }
  *(ushort4v*)(TH + (long)(n0 + n) * DM + k0 + k) = h;
  *(ushort4v*)(TL + (long)(n0 + n) * DM + k0 + k) = l;
}

// ---------------------------------------------------------------------------
// Fused QKV projection (MFMA): grid.z = 6 -> (src 0..2) x (batch 0..1)
// ---------------------------------------------------------------------------
struct MfmaProjArgs {
  const float* A[3];
  long astride[3];
  const unsigned short* BTh[3];
  const unsigned short* BTl[3];
  const float* bias[3];
  float* C[3];
};

__global__ __launch_bounds__(256) void proj_mfma_kernel(MfmaProjArgs p) {
  const int z = blockIdx.z, sel = z >> 1, b = z & 1;
  const float* A = p.A[sel] + (long)b * p.astride[sel];
  float* C = p.C[sel] + (long)b * SEQ * DM;
  mfma_gemm(A, DM, p.BTh[sel], p.BTl[sel], DM, p.bias[sel], C, DM, DM,
            blockIdx.y * 64, blockIdx.x * 128);
}

__global__ __launch_bounds__(256) void out_mfma_kernel(
    const float* __restrict__ ohs,
    const unsigned short* __restrict__ WoTh,
    const unsigned short* __restrict__ WoTl,
    const float* __restrict__ bo, float* __restrict__ out0) {
  const int b = blockIdx.z;
  mfma_gemm(ohs + (long)b * SEQ * DM, DM, WoTh, WoTl, DM, bo,
            out0 + (long)b * SEQ * DM, DM, DM,
            blockIdx.y * 64, blockIdx.x * 128);
}

// ---------------------------------------------------------------------------
// Scores: per (b,h): S = Qh * Kh^T, epilogue relu(S/8) + mask*-1e9 (f32 vector)
// ---------------------------------------------------------------------------
__device__ __forceinline__ float score_ep(float a, int m) {
  float s = fmaxf(a * 0.125f, 0.f);
  return m ? (s - 1e9f) : s;
}

__global__ __launch_bounds__(256) void scores_kernel(
    const float* __restrict__ qq, const float* __restrict__ kk,
    const int* __restrict__ mask, float* __restrict__ attw)
{
  const int z = blockIdx.z;           // b*16 + h
  const int b = z >> 4, h = z & 15;
  const float* Aq = qq + (long)b * (SEQ * DM) + h * DH;
  const float* Bk = kk + (long)b * (SEQ * DM) + h * DH;
  const int*   mk = mask + (long)b * (SEQ * SEQ);
  float* out = attw + (long)z * (SEQ * SEQ);

  constexpr int BM = 128, BK = 16, TM = 8, TN = 8;
  __shared__ float Qs[BK][BM];
  __shared__ float Ks[BK][BM];
  const int tid = threadIdx.x, tx = tid & 15, ty = tid >> 4;
  const int row0 = blockIdx.y * BM, col0 = blockIdx.x * BM;

  float acc[TM][TN];
#pragma unroll
  for (int i = 0; i < TM; i++)
#pragma unroll
    for (int j = 0; j < TN; j++) acc[i][j] = 0.f;

  const int ar = tid >> 1;
  const int ac = (tid & 1) * 8;

  for (int k0 = 0; k0 < DH; k0 += BK) {
    {
      const float* ap = Aq + (long)(row0 + ar) * DM + k0 + ac;
      float4 v0 = *(const float4*)ap;
      float4 v1 = *(const float4*)(ap + 4);
      Qs[ac + 0][ar] = v0.x; Qs[ac + 1][ar] = v0.y;
      Qs[ac + 2][ar] = v0.z; Qs[ac + 3][ar] = v0.w;
      Qs[ac + 4][ar] = v1.x; Qs[ac + 5][ar] = v1.y;
      Qs[ac + 6][ar] = v1.z; Qs[ac + 7][ar] = v1.w;
    }
    {
      const float* bp = Bk + (long)(col0 + ar) * DM + k0 + ac;
      float4 v0 = *(const float4*)bp;
      float4 v1 = *(const float4*)(bp + 4);
      Ks[ac + 0][ar] = v0.x; Ks[ac + 1][ar] = v0.y;
      Ks[ac + 2][ar] = v0.z; Ks[ac + 3][ar] = v0.w;
      Ks[ac + 4][ar] = v1.x; Ks[ac + 5][ar] = v1.y;
      Ks[ac + 6][ar] = v1.z; Ks[ac + 7][ar] = v1.w;
    }
    __syncthreads();
#pragma unroll
    for (int kk2 = 0; kk2 < BK; kk2++) {
      float a[TM], w[TN];
#pragma unroll
      for (int i = 0; i < TM; i++) a[i] = Qs[kk2][ty * TM + i];
#pragma unroll
      for (int j = 0; j < TN; j++) w[j] = Ks[kk2][tx * TN + j];
#pragma unroll
      for (int i = 0; i < TM; i++)
#pragma unroll
        for (int j = 0; j < TN; j++)
          acc[i][j] = fmaf(a[i], w[j], acc[i][j]);
    }
    __syncthreads();
  }

#pragma unroll
  for (int i = 0; i < TM; i++) {
    const int r = row0 + ty * TM + i;
    const int c = col0 + tx * TN;
    const int4* mp = (const int4*)(mk + (long)r * SEQ + c);
    int4 m0 = mp[0], m1 = mp[1];
    float4 v0, v1;
    v0.x = score_ep(acc[i][0], m0.x); v0.y = score_ep(acc[i][1], m0.y);
    v0.z = score_ep(acc[i][2], m0.z); v0.w = score_ep(acc[i][3], m0.w);
    v1.x = score_ep(acc[i][4], m1.x); v1.y = score_ep(acc[i][5], m1.y);
    v1.z = score_ep(acc[i][6], m1.z); v1.w = score_ep(acc[i][7], m1.w);
    float* op = out + (long)r * SEQ + c;
    *(float4*)op       = v0;
    *(float4*)(op + 4) = v1;
  }
}

// ---------------------------------------------------------------------------
// In-place row softmax. 1 block (256 thr) per row of 1024.
// ---------------------------------------------------------------------------
__global__ __launch_bounds__(256) void softmax_kernel(float* __restrict__ attw)
{
  const long g = blockIdx.x;
  float* row = attw + g * SEQ;
  const int tid = threadIdx.x;
  float4 v = *(float4*)(row + tid * 4);

  float m = fmaxf(fmaxf(v.x, v.y), fmaxf(v.z, v.w));
#pragma unroll
  for (int o = 32; o >= 1; o >>= 1) m = fmaxf(m, __shfl_xor(m, o, 64));
  __shared__ float redm[4];
  const int wave = tid >> 6, lane = tid & 63;
  if (lane == 0) redm[wave] = m;
  __syncthreads();
  m = fmaxf(fmaxf(redm[0], redm[1]), fmaxf(redm[2], redm[3]));

  v.x = __expf(v.x - m); v.y = __expf(v.y - m);
  v.z = __expf(v.z - m); v.w = __expf(v.w - m);
  float s = v.x + v.y + v.z + v.w;
#pragma unroll
  for (int o = 32; o >= 1; o >>= 1) s += __shfl_xor(s, o, 64);
  __shared__ float reds[4];
  if (lane == 0) reds[wave] = s;
  __syncthreads();
  s = reds[0] + reds[1] + reds[2] + reds[3];

  const float inv = 1.0f / s;
  v.x *= inv; v.y *= inv; v.z *= inv; v.w *= inv;
  *(float4*)(row + tid * 4) = v;
}

// ---------------------------------------------------------------------------
// f32 tiled GEMM body (kept for PV): C[BMxBN] = A[BMxK] * W[KxBN]
// ---------------------------------------------------------------------------
template<int BN, int TN>
__device__ __forceinline__ void gemm_body(
    const float* __restrict__ A, int lda,
    const float* __restrict__ W, int ldw,
    const float* __restrict__ bias,
    float* __restrict__ C, int ldc, int K)
{
  constexpr int BM = 128, BK = 16, TM = 8;
  __shared__ float As[BK][BM];
  __shared__ float Ws[BK][BN];

  const int tid = threadIdx.x;
  const int tx  = tid & 15;
  const int ty  = tid >> 4;
  const int row0 = blockIdx.y * BM;
  const int col0 = blockIdx.x * BN;

  float acc[TM][TN];
#pragma unroll
  for (int i = 0; i < TM; i++)
#pragma unroll
    for (int j = 0; j < TN; j++) acc[i][j] = 0.f;

  const int ar = tid >> 1;
  const int ac = (tid & 1) * 8;

  for (int k0 = 0; k0 < K; k0 += BK) {
    {
      const float* ap = A + (long)(row0 + ar) * lda + (k0 + ac);
      float4 v0 = *(const float4*)ap;
      float4 v1 = *(const float4*)(ap + 4);
      As[ac + 0][ar] = v0.x; As[ac + 1][ar] = v0.y;
      As[ac + 2][ar] = v0.z; As[ac + 3][ar] = v0.w;
      As[ac + 4][ar] = v1.x; As[ac + 5][ar] = v1.y;
      As[ac + 6][ar] = v1.z; As[ac + 7][ar] = v1.w;
    }
    {
      constexpr int PER = BK * BN / 256;
      const int wr = (tid * PER) / BN;
      const int wc = (tid * PER) % BN;
      const float* wp = W + (long)(k0 + wr) * ldw + col0 + wc;
      if constexpr (PER == 8) {
        *(float4*)&Ws[wr][wc]     = *(const float4*)wp;
        *(float4*)&Ws[wr][wc + 4] = *(const float4*)(wp + 4);
      } else {
        *(float4*)&Ws[wr][wc]     = *(const float4*)wp;
      }
    }
    __syncthreads();
#pragma unroll
    for (int kk = 0; kk < BK; kk++) {
      float a[TM], w[TN];
#pragma unroll
      for (int i = 0; i < TM; i++) a[i] = As[kk][ty * TM + i];
#pragma unroll
      for (int j = 0; j < TN; j++) w[j] = Ws[kk][tx * TN + j];
#pragma unroll
      for (int i = 0; i < TM; i++)
#pragma unroll
        for (int j = 0; j < TN; j++)
          acc[i][j] = fmaf(a[i], w[j], acc[i][j]);
    }
    __syncthreads();
  }

#pragma unroll
  for (int i = 0; i < TM; i++) {
    const int r = row0 + ty * TM + i;
    float* cp = C + (long)r * ldc + col0 + tx * TN;
#pragma unroll
    for (int j = 0; j < TN; j += 4) {
      float4 v;
      v.x = acc[i][j + 0]; v.y = acc[i][j + 1];
      v.z = acc[i][j + 2]; v.w = acc[i][j + 3];
      if (bias) {
        const float* bp = bias + col0 + tx * TN + j;
        v.x += bp[0]; v.y += bp[1]; v.z += bp[2]; v.w += bp[3];
      }
      *(float4*)(cp + j) = v;
    }
  }
}

__global__ __launch_bounds__(256) void pv_kernel(
    const float* __restrict__ attw, const float* __restrict__ vv,
    float* __restrict__ out_hs)
{
  const int z = blockIdx.z, b = z >> 4, h = z & 15;
  gemm_body<64, 4>(attw + (long)z * (SEQ * SEQ), SEQ,
                   vv + (long)b * (SEQ * DM) + h * DH, DM,
                   nullptr,
                   out_hs + (long)b * (SEQ * DM) + h * DH, DM, SEQ);
}

// ---------------------------------------------------------------------------
extern "C" void kernel_launch(void* const* d_in, const int* in_sizes, int n_in,
                              void* d_out, int out_size, void* d_ws, size_t ws_size,
                              hipStream_t stream)
{
  const float* v    = (const float*)d_in[0];
  const float* k    = (const float*)d_in[1];
  const float* q    = (const float*)d_in[2];
  const int*   mask = (const int*)  d_in[3];
  const float* Wq   = (const float*)d_in[4];
  const float* bq   = (const float*)d_in[5];
  const float* Wk   = (const float*)d_in[6];
  const float* bk   = (const float*)d_in[7];
  const float* Wv   = (const float*)d_in[8];
  const float* bv   = (const float*)d_in[9];
  const float* Wo   = (const float*)d_in[10];
  const float* bo   = (const float*)d_in[11];

  const long NE = (long)SEQ * DM;          // 1M elements
  // ws layout (f32): qq | kk | vv | ohs | WoTh | WoTl   (37.75 MB)
  float* qq  = (float*)d_ws;
  float* kkp = qq  + BATCH * NE;
  float* vvp = kkp + BATCH * NE;
  float* ohs = vvp + BATCH * NE;
  unsigned short* WoTh = (unsigned short*)(ohs + BATCH * NE);
  unsigned short* WoTl = WoTh + NE;

  float* out0 = (float*)d_out;                       // (B,1024,1024)
  float* attw = out0 + BATCH * NE;                   // (B,16,1024,1024)

  // Stash QKV weight splits in the TAIL of the att region (12.6 MB).
  // Timeline: splitT -> proj (reads stash) -> scores (overwrites stash with
  // real att weights). Stream-serialized, graph-safe, rewritten every launch.
  unsigned short* stash = (unsigned short*)(attw + (long)BATCH * NH * SEQ * SEQ)
                          - 6L * NE;
  unsigned short* WqTh = stash;
  unsigned short* WqTl = WqTh + NE;
  unsigned short* WkTh = WqTl + NE;
  unsigned short* WkTl = WkTh + NE;
  unsigned short* WvTh = WkTl + NE;
  unsigned short* WvTl = WvTh + NE;

  dim3 blk(256);

  SplitTArgs st;
  st.W[0] = Wq; st.W[1] = Wk; st.W[2] = Wv; st.W[3] = Wo;
  st.TH[0] = WqTh; st.TH[1] = WkTh; st.TH[2] = WvTh; st.TH[3] = WoTh;
  st.TL[0] = WqTl; st.TL[1] = WkTl; st.TL[2] = WvTl; st.TL[3] = WoTl;
  hipLaunchKernelGGL(splitT_kernel, dim3(32, 32, 4), blk, 0, stream, st);

  MfmaProjArgs p;
  p.A[0] = q + DM;  p.A[1] = k;   p.A[2] = v;        // q skips row 0
  p.astride[0] = 1025L * DM; p.astride[1] = 1025L * DM; p.astride[2] = 1024L * DM;
  p.BTh[0] = WqTh; p.BTh[1] = WkTh; p.BTh[2] = WvTh;
  p.BTl[0] = WqTl; p.BTl[1] = WkTl; p.BTl[2] = WvTl;
  p.bias[0] = bq;  p.bias[1] = bk;  p.bias[2] = bv;
  p.C[0] = qq;     p.C[1] = kkp;    p.C[2] = vvp;
  hipLaunchKernelGGL(proj_mfma_kernel, dim3(8, 16, 6), blk, 0, stream, p);

  hipLaunchKernelGGL(scores_kernel, dim3(8, 8, 32), blk, 0, stream, qq, kkp, mask, attw);
  hipLaunchKernelGGL(softmax_kernel, dim3(BATCH * NH * SEQ), blk, 0, stream, attw);
  hipLaunchKernelGGL(pv_kernel, dim3(1, 8, 32), blk, 0, stream, attw, vvp, ohs);
  hipLaunchKernelGGL(out_mfma_kernel, dim3(8, 16, 2), blk, 0, stream, ohs, WoTh, WoTl, bo, out0);
}

// Round 3
// 385.828 us; speedup vs baseline: 1.8134x; 1.1788x over previous
//
#include <hip/hip_runtime.h>

#define DM   1024
#define NH   16
#define DH   64
#define BATCH 2
#define SEQ  1024
#define QBLK 128
#define KBLK 128

typedef __attribute__((ext_vector_type(8))) short   short8;
typedef __attribute__((ext_vector_type(4))) float   f32x4;
typedef __attribute__((ext_vector_type(4))) unsigned short ushort4v;

// ---- bf16 helpers (RNE) ----
__device__ __forceinline__ unsigned short f2bf(float f) {
  unsigned int u = __float_as_uint(f);
  u += 0x7FFFu + ((u >> 16) & 1u);
  return (unsigned short)(u >> 16);
}
__device__ __forceinline__ float bf2f(unsigned short h) {
  return __uint_as_float(((unsigned int)h) << 16);
}
__device__ __forceinline__ void split8(const float4& a, const float4& b,
                                       short8& h, short8& l) {
  float f[8] = {a.x, a.y, a.z, a.w, b.x, b.y, b.z, b.w};
#pragma unroll
  for (int j = 0; j < 8; j++) {
    unsigned short hh = f2bf(f[j]);
    h[j] = (short)hh;
    l[j] = (short)f2bf(f[j] - bf2f(hh));
  }
}

// ---------------------------------------------------------------------------
// Split-bf16 MFMA GEMM (projections + output): C = A(f32) * BT(hi/lo) + bias
// BM=64, BN=128, BK=32, 256 thr = 4 waves. 3-term emulation.
// ---------------------------------------------------------------------------
__device__ __forceinline__ void mfma_gemm(
    const float* __restrict__ A, long lda,
    const unsigned short* __restrict__ BTh,
    const unsigned short* __restrict__ BTl, long ldb,
    const float* __restrict__ bias, float* __restrict__ C, long ldc,
    int K, int row0, int col0)
{
  __shared__ short Ah[4][64][8];
  __shared__ short Al[4][64][8];
  __shared__ short Bh[8][64][8];
  __shared__ short Bl[8][64][8];

  const int tid  = threadIdx.x;
  const int wave = tid >> 6, lane = tid & 63;
  const int wm = wave & 1, wn = wave >> 1;

  f32x4 acc[2][4];
#pragma unroll
  for (int i = 0; i < 2; i++)
#pragma unroll
    for (int j = 0; j < 4; j++) acc[i][j] = (f32x4){0.f, 0.f, 0.f, 0.f};

  const int am    = tid >> 2;
  const int ako   = (tid & 3) * 8;
  const int afrag = am >> 4;
  const int alane = (am & 15) + (ako >> 3) * 16;
  const int bn     = tid >> 1;
  const int bkh    = tid & 1;
  const int bfrag  = bn >> 4;
  const int blane0 = (bn & 15) + (bkh * 2) * 16;

  const float*          aptr  = A   + (long)(row0 + am) * lda + ako;
  const unsigned short* bhptr = BTh + (long)(col0 + bn) * ldb + bkh * 16;
  const unsigned short* blptr = BTl + (long)(col0 + bn) * ldb + bkh * 16;

  for (int k0 = 0; k0 < K; k0 += 32) {
    float4 v0 = *(const float4*)(aptr + k0);
    float4 v1 = *(const float4*)(aptr + k0 + 4);
    short8 hv, lv;
    split8(v0, v1, hv, lv);
    *(short8*)&Ah[afrag][alane][0] = hv;
    *(short8*)&Al[afrag][alane][0] = lv;
    short8 b0 = *(const short8*)(bhptr + k0);
    short8 b1 = *(const short8*)(bhptr + k0 + 8);
    short8 c0 = *(const short8*)(blptr + k0);
    short8 c1 = *(const short8*)(blptr + k0 + 8);
    *(short8*)&Bh[bfrag][blane0][0]      = b0;
    *(short8*)&Bh[bfrag][blane0 + 16][0] = b1;
    *(short8*)&Bl[bfrag][blane0][0]      = c0;
    *(short8*)&Bl[bfrag][blane0 + 16][0] = c1;
    __syncthreads();

    short8 a_h[2], a_l[2], b_h[4], b_l[4];
#pragma unroll
    for (int fm = 0; fm < 2; fm++) {
      a_h[fm] = *(short8*)&Ah[wm * 2 + fm][lane][0];
      a_l[fm] = *(short8*)&Al[wm * 2 + fm][lane][0];
    }
#pragma unroll
    for (int fn = 0; fn < 4; fn++) {
      b_h[fn] = *(short8*)&Bh[wn * 4 + fn][lane][0];
      b_l[fn] = *(short8*)&Bl[wn * 4 + fn][lane][0];
    }
#pragma unroll
    for (int fm = 0; fm < 2; fm++)
#pragma unroll
      for (int fn = 0; fn < 4; fn++) {
        acc[fm][fn] = __builtin_amdgcn_mfma_f32_16x16x32_bf16(
            a_h[fm], b_h[fn], acc[fm][fn], 0, 0, 0);
        acc[fm][fn] = __builtin_amdgcn_mfma_f32_16x16x32_bf16(
            a_h[fm], b_l[fn], acc[fm][fn], 0, 0, 0);
        acc[fm][fn] = __builtin_amdgcn_mfma_f32_16x16x32_bf16(
            a_l[fm], b_h[fn], acc[fm][fn], 0, 0, 0);
      }
    __syncthreads();
  }

  const int erow = (lane >> 4) * 4;
  const int ecol = lane & 15;
#pragma unroll
  for (int fm = 0; fm < 2; fm++)
#pragma unroll
    for (int fn = 0; fn < 4; fn++) {
      const int r0 = row0 + wm * 32 + fm * 16 + erow;
      const int cc = col0 + wn * 64 + fn * 16 + ecol;
      const float b = bias ? bias[cc] : 0.f;
#pragma unroll
      for (int i = 0; i < 4; i++)
        C[(long)(r0 + i) * ldc + cc] = acc[fm][fn][i] + b;
    }
}

// ---------------------------------------------------------------------------
// Weight split+transpose: W[K][N] f32 -> TH/TL[N][K] bf16 hi/lo
// ---------------------------------------------------------------------------
struct SplitTArgs {
  const float* W[4];
  unsigned short* TH[4];
  unsigned short* TL[4];
};

__global__ __launch_bounds__(256) void splitT_kernel(SplitTArgs s) {
  const int w = blockIdx.z;
  const float* W = s.W[w];
  unsigned short* TH = s.TH[w];
  unsigned short* TL = s.TL[w];
  __shared__ float tile[32][33];
  const int t = threadIdx.x;
  const int k0 = blockIdx.y * 32, n0 = blockIdx.x * 32;
  {
    const int r = t >> 3, c = (t & 7) * 4;
    float4 v = *(const float4*)(W + (long)(k0 + r) * DM + n0 + c);
    tile[r][c] = v.x; tile[r][c + 1] = v.y;
    tile[r][c + 2] = v.z; tile[r][c + 3] = v.w;
  }
  __syncthreads();
  const int n = t >> 3, k = (t & 7) * 4;
  ushort4v h, l;
#pragma unroll
  for (int i = 0; i < 4; i++) {
    float f = tile[k + i][n];
    unsigned short hh = f2bf(f);
    h[i] = hh;
    l[i] = f2bf(f - bf2f(hh));
  }
  *(ushort4v*)(TH + (long)(n0 + n) * DM + k0 + k) = h;
  *(ushort4v*)(TL + (long)(n0 + n) * DM + k0 + k) = l;
}

// ---------------------------------------------------------------------------
// Fused QKV projection (MFMA)
// ---------------------------------------------------------------------------
struct MfmaProjArgs {
  const float* A[3];
  long astride[3];
  const unsigned short* BTh[3];
  const unsigned short* BTl[3];
  const float* bias[3];
  float* C[3];
};

__global__ __launch_bounds__(256) void proj_mfma_kernel(MfmaProjArgs p) {
  const int z = blockIdx.z, sel = z >> 1, b = z & 1;
  const float* A = p.A[sel] + (long)b * p.astride[sel];
  float* C = p.C[sel] + (long)b * SEQ * DM;
  mfma_gemm(A, DM, p.BTh[sel], p.BTl[sel], DM, p.bias[sel], C, DM, DM,
            blockIdx.y * 64, blockIdx.x * 128);
}

__global__ __launch_bounds__(256) void out_mfma_kernel(
    const float* __restrict__ ohs,
    const unsigned short* __restrict__ WoTh,
    const unsigned short* __restrict__ WoTl,
    const float* __restrict__ bo, float* __restrict__ out0) {
  const int b = blockIdx.z;
  mfma_gemm(ohs + (long)b * SEQ * DM, DM, WoTh, WoTl, DM, bo,
            out0 + (long)b * SEQ * DM, DM, DM,
            blockIdx.y * 64, blockIdx.x * 128);
}

// ---------------------------------------------------------------------------
// Fused attention: per (b,h,128-row strip): scores -> softmax -> att write -> PV
// 512 threads = 8 waves; wave w owns q-rows 16w..16w+15.
// Phase A: l(row sums) via plain-bf16 QK^T (denominator only, 0.2% rel err OK).
// Phase B: split-bf16 QK^T (3-term), P=exp(.)*linv written to att (f32),
//          O += P*V with split P and V (3-term).
// No max-subtraction: post-relu logits in [0,~10] or -1e9 (exp underflows to 0),
// matching the f64 reference exactly after softmax cancellation.
// ---------------------------------------------------------------------------
__global__ __launch_bounds__(512) void fused_attn_kernel(
    const float* __restrict__ qq, const float* __restrict__ kk,
    const float* __restrict__ vv, const int* __restrict__ mask,
    float* __restrict__ attw, float* __restrict__ ohs)
{
  const int z = blockIdx.y;          // b*16+h
  const int b = z >> 4, h = z & 15;
  const int row0 = blockIdx.x * QBLK;

  const float* Q = qq + (long)b * SEQ * DM + h * DH;
  const float* K = kk + (long)b * SEQ * DM + h * DH;
  const float* V = vv + (long)b * SEQ * DM + h * DH;
  const int*  mk = mask + (long)b * SEQ * SEQ;
  float* att  = attw + (long)z * SEQ * SEQ;
  float* ohsb = ohs + (long)b * SEQ * DM + h * DH;

  // 130 KB LDS (gfx950 allows up to 160 KB/workgroup)
  __shared__ short Kh[8][2][64][8];   // 16 KB  K-tile hi  [nfrag][khalf][lane][8]
  __shared__ short Kl[8][2][64][8];   // 16 KB  K-tile lo
  __shared__ short Vh[4][4][64][8];   // 16 KB  V-tile hi  [ks][dfrag][lane][8]
  __shared__ short Vl[4][4][64][8];   // 16 KB  V-tile lo
  __shared__ float P[8][16][132];     // 66 KB  per-wave P tile (padded rows)

  const int tid  = threadIdx.x;
  const int w    = tid >> 6, lane = tid & 63;
  const int lg   = lane >> 4, lr = lane & 15;
  const int grow = row0 + 16 * w + 4 * lg;   // +i for acc elem i

  // ---- Q fragments (held in registers for the whole kernel) ----
  short8 qh[2], ql[2];
  {
    const float* qp = Q + (long)(row0 + 16 * w + lr) * DM + 8 * lg;
#pragma unroll
    for (int kh = 0; kh < 2; kh++) {
      float4 a = *(const float4*)(qp + 32 * kh);
      float4 bq = *(const float4*)(qp + 32 * kh + 4);
      split8(a, bq, qh[kh], ql[kh]);
    }
  }

  // ================= Phase A: row sums =================
  float lsum[4] = {0.f, 0.f, 0.f, 0.f};
  for (int t = 0; t < 8; t++) {
    {
      const int key = tid >> 2, d0 = (tid & 3) * 16;
      const float* kp = K + (long)(t * KBLK + key) * DM + d0;
#pragma unroll
      for (int oct = 0; oct < 2; oct++) {
        const int d = d0 + 8 * oct;
        float4 x = *(const float4*)(kp + 8 * oct);
        float4 y = *(const float4*)(kp + 8 * oct + 4);
        short8 hs;
        float f[8] = {x.x, x.y, x.z, x.w, y.x, y.y, y.z, y.w};
#pragma unroll
        for (int j = 0; j < 8; j++) hs[j] = (short)f2bf(f[j]);
        *(short8*)&Kh[key >> 4][d >> 5][(key & 15) + 16 * ((d & 31) >> 3)][0] = hs;
      }
    }
    __syncthreads();

    f32x4 s[8];
#pragma unroll
    for (int nf = 0; nf < 8; nf++) s[nf] = (f32x4){0.f, 0.f, 0.f, 0.f};
#pragma unroll
    for (int nf = 0; nf < 8; nf++)
#pragma unroll
      for (int kh = 0; kh < 2; kh++) {
        short8 kf = *(short8*)&Kh[nf][kh][lane][0];
        s[nf] = __builtin_amdgcn_mfma_f32_16x16x32_bf16(qh[kh], kf, s[nf], 0, 0, 0);
      }
#pragma unroll
    for (int nf = 0; nf < 8; nf++)
#pragma unroll
      for (int i = 0; i < 4; i++) {
        int m = mk[(long)(grow + i) * SEQ + t * KBLK + 16 * nf + lr];
        float se = fmaxf(s[nf][i] * 0.125f, 0.f) - 1e9f * (float)m;
        lsum[i] += __expf(se);
      }
    __syncthreads();
  }
  // reduce across the 16 lanes sharing the same row group
#pragma unroll
  for (int o = 1; o <= 8; o <<= 1)
#pragma unroll
    for (int i = 0; i < 4; i++)
      lsum[i] += __shfl_xor(lsum[i], o, 64);
  float linv[4];
#pragma unroll
  for (int i = 0; i < 4; i++) linv[i] = 1.f / lsum[i];

  // ================= Phase B: att write + PV =================
  f32x4 o_acc[4];
#pragma unroll
  for (int nf = 0; nf < 4; nf++) o_acc[nf] = (f32x4){0.f, 0.f, 0.f, 0.f};

  for (int t = 0; t < 8; t++) {
    // ---- stage K (hi+lo) ----
    {
      const int key = tid >> 2, d0 = (tid & 3) * 16;
      const float* kp = K + (long)(t * KBLK + key) * DM + d0;
#pragma unroll
      for (int oct = 0; oct < 2; oct++) {
        const int d = d0 + 8 * oct;
        float4 x = *(const float4*)(kp + 8 * oct);
        float4 y = *(const float4*)(kp + 8 * oct + 4);
        short8 hs, ls;
        split8(x, y, hs, ls);
        const int nf2 = key >> 4, kh2 = d >> 5;
        const int ln2 = (key & 15) + 16 * ((d & 31) >> 3);
        *(short8*)&Kh[nf2][kh2][ln2][0] = hs;
        *(short8*)&Kl[nf2][kh2][ln2][0] = ls;
      }
    }
    // ---- stage V (hi+lo, frag-ordered transpose) ----
#pragma unroll
    for (int r = 0; r < 4; r++) {
      const int idx = tid + 512 * r;             // 0..2047 float4 chunks
      const int key = idx >> 4, d0 = (idx & 15) * 4;
      float4 x = *(const float4*)(V + (long)(t * KBLK + key) * DM + d0);
      const int ks = key >> 5, kin = key & 31;
      const int g2 = kin >> 3, j2 = kin & 7;
      float f[4] = {x.x, x.y, x.z, x.w};
#pragma unroll
      for (int i = 0; i < 4; i++) {
        const int d = d0 + i;
        unsigned short hh = f2bf(f[i]);
        Vh[ks][d >> 4][(d & 15) + 16 * g2][j2] = (short)hh;
        Vl[ks][d >> 4][(d & 15) + 16 * g2][j2] = (short)f2bf(f[i] - bf2f(hh));
      }
    }
    __syncthreads();

    // ---- S = Q K^T, split 3-term ----
    f32x4 s[8];
#pragma unroll
    for (int nf = 0; nf < 8; nf++) s[nf] = (f32x4){0.f, 0.f, 0.f, 0.f};
#pragma unroll
    for (int nf = 0; nf < 8; nf++)
#pragma unroll
      for (int kh = 0; kh < 2; kh++) {
        short8 kfh = *(short8*)&Kh[nf][kh][lane][0];
        short8 kfl = *(short8*)&Kl[nf][kh][lane][0];
        s[nf] = __builtin_amdgcn_mfma_f32_16x16x32_bf16(qh[kh], kfh, s[nf], 0, 0, 0);
        s[nf] = __builtin_amdgcn_mfma_f32_16x16x32_bf16(qh[kh], kfl, s[nf], 0, 0, 0);
        s[nf] = __builtin_amdgcn_mfma_f32_16x16x32_bf16(ql[kh], kfh, s[nf], 0, 0, 0);
      }

    // ---- epilogue: P = exp(relu(S/8) - 1e9*mask) * linv -> per-wave LDS ----
#pragma unroll
    for (int nf = 0; nf < 8; nf++)
#pragma unroll
      for (int i = 0; i < 4; i++) {
        int m = mk[(long)(grow + i) * SEQ + t * KBLK + 16 * nf + lr];
        float se = fmaxf(s[nf][i] * 0.125f, 0.f) - 1e9f * (float)m;
        P[w][4 * lg + i][16 * nf + lr] = __expf(se) * linv[i];
      }

    // ---- P A-frags (row = lr, keys 32ks+8lg..+7), split hi/lo ----
    short8 pah[4], pal[4];
#pragma unroll
    for (int ks = 0; ks < 4; ks++) {
      float4 x = *(float4*)&P[w][lr][32 * ks + 8 * lg];
      float4 y = *(float4*)&P[w][lr][32 * ks + 8 * lg + 4];
      split8(x, y, pah[ks], pal[ks]);
    }

    // ---- PV MFMA (3-term) ----
#pragma unroll
    for (int ks = 0; ks < 4; ks++)
#pragma unroll
      for (int nf = 0; nf < 4; nf++) {
        short8 vfh = *(short8*)&Vh[ks][nf][lane][0];
        short8 vfl = *(short8*)&Vl[ks][nf][lane][0];
        o_acc[nf] = __builtin_amdgcn_mfma_f32_16x16x32_bf16(pah[ks], vfh, o_acc[nf], 0, 0, 0);
        o_acc[nf] = __builtin_amdgcn_mfma_f32_16x16x32_bf16(pah[ks], vfl, o_acc[nf], 0, 0, 0);
        o_acc[nf] = __builtin_amdgcn_mfma_f32_16x16x32_bf16(pal[ks], vfh, o_acc[nf], 0, 0, 0);
      }

    // ---- att output write (coalesced 128B rows from LDS) ----
#pragma unroll
    for (int rh = 0; rh < 2; rh++)
#pragma unroll
      for (int rr = 0; rr < 4; rr++) {
        const int rl = 8 * rh + (lane >> 3);
        const int c4 = (lane & 7) + 8 * rr;
        float4 pv4 = *(float4*)&P[w][rl][4 * c4];
        *(float4*)(att + (long)(row0 + 16 * w + rl) * SEQ + t * KBLK + 4 * c4) = pv4;
      }
    __syncthreads();
  }

  // ---- O write ----
#pragma unroll
  for (int nf = 0; nf < 4; nf++)
#pragma unroll
    for (int i = 0; i < 4; i++)
      ohsb[(long)(grow + i) * DM + 16 * nf + lr] = o_acc[nf][i];
}

// ---------------------------------------------------------------------------
extern "C" void kernel_launch(void* const* d_in, const int* in_sizes, int n_in,
                              void* d_out, int out_size, void* d_ws, size_t ws_size,
                              hipStream_t stream)
{
  const float* v    = (const float*)d_in[0];
  const float* k    = (const float*)d_in[1];
  const float* q    = (const float*)d_in[2];
  const int*   mask = (const int*)  d_in[3];
  const float* Wq   = (const float*)d_in[4];
  const float* bq   = (const float*)d_in[5];
  const float* Wk   = (const float*)d_in[6];
  const float* bk   = (const float*)d_in[7];
  const float* Wv   = (const float*)d_in[8];
  const float* bv   = (const float*)d_in[9];
  const float* Wo   = (const float*)d_in[10];
  const float* bo   = (const float*)d_in[11];

  const long NE = (long)SEQ * DM;
  float* qq  = (float*)d_ws;
  float* kkp = qq  + BATCH * NE;
  float* vvp = kkp + BATCH * NE;
  float* ohs = vvp + BATCH * NE;
  unsigned short* WoTh = (unsigned short*)(ohs + BATCH * NE);
  unsigned short* WoTl = WoTh + NE;

  float* out0 = (float*)d_out;
  float* attw = out0 + BATCH * NE;

  // QKV weight splits stashed in the att-region tail; proj reads them BEFORE
  // fused_attn overwrites that region (stream-serialized, graph-safe).
  unsigned short* stash = (unsigned short*)(attw + (long)BATCH * NH * SEQ * SEQ)
                          - 6L * NE;
  unsigned short* WqTh = stash;
  unsigned short* WqTl = WqTh + NE;
  unsigned short* WkTh = WqTl + NE;
  unsigned short* WkTl = WkTh + NE;
  unsigned short* WvTh = WkTl + NE;
  unsigned short* WvTl = WvTh + NE;

  dim3 blk(256);

  SplitTArgs st;
  st.W[0] = Wq; st.W[1] = Wk; st.W[2] = Wv; st.W[3] = Wo;
  st.TH[0] = WqTh; st.TH[1] = WkTh; st.TH[2] = WvTh; st.TH[3] = WoTh;
  st.TL[0] = WqTl; st.TL[1] = WkTl; st.TL[2] = WvTl; st.TL[3] = WoTl;
  hipLaunchKernelGGL(splitT_kernel, dim3(32, 32, 4), blk, 0, stream, st);

  MfmaProjArgs p;
  p.A[0] = q + DM;  p.A[1] = k;   p.A[2] = v;
  p.astride[0] = 1025L * DM; p.astride[1] = 1025L * DM; p.astride[2] = 1024L * DM;
  p.BTh[0] = WqTh; p.BTh[1] = WkTh; p.BTh[2] = WvTh;
  p.BTl[0] = WqTl; p.BTl[1] = WkTl; p.BTl[2] = WvTl;
  p.bias[0] = bq;  p.bias[1] = bk;  p.bias[2] = bv;
  p.C[0] = qq;     p.C[1] = kkp;    p.C[2] = vvp;
  hipLaunchKernelGGL(proj_mfma_kernel, dim3(8, 16, 6), blk, 0, stream, p);

  hipLaunchKernelGGL(fused_attn_kernel, dim3(SEQ / QBLK, BATCH * NH),
                     dim3(512), 0, stream, qq, kkp, vvp, mask, attw, ohs);

  hipLaunchKernelGGL(out_mfma_kernel, dim3(8, 16, 2), blk, 0, stream,
                     ohs, WoTh, WoTl, bo, out0);
}

// Round 6
// 385.247 us; speedup vs baseline: 1.8162x; 1.0015x over previous
//
#include <hip/hip_runtime.h>

#define DM   1024
#define NH   16
#define DH   64
#define BATCH 2
#define SEQ  1024

typedef __attribute__((ext_vector_type(8))) short   short8;
typedef __attribute__((ext_vector_type(4))) float   f32x4;
typedef __attribute__((ext_vector_type(4))) unsigned short ushort4v;
typedef unsigned short u16;
typedef unsigned int   u32;

// ---- bf16 helpers (RNE) ----
__device__ __forceinline__ u16 f2bf(float f) {
  unsigned int u = __float_as_uint(f);
  u += 0x7FFFu + ((u >> 16) & 1u);
  return (u16)(u >> 16);
}
__device__ __forceinline__ float bf2f(u16 h) {
  return __uint_as_float(((unsigned int)h) << 16);
}
__device__ __forceinline__ void split8(const float4& a, const float4& b,
                                       short8& h, short8& l) {
  float f[8] = {a.x, a.y, a.z, a.w, b.x, b.y, b.z, b.w};
#pragma unroll
  for (int j = 0; j < 8; j++) {
    u16 hh = f2bf(f[j]);
    h[j] = (short)hh;
    l[j] = (short)f2bf(f[j] - bf2f(hh));
  }
}

// ---------------------------------------------------------------------------
// Split-bf16 MFMA GEMM, A pre-split in global (bf16 hi/lo [row][k]),
// B pre-split transposed [n][k]. BM=64, BN=128, BK=32, 256 thr = 4 waves.
// 3-term emulation: hi*hi + hi*lo + lo*hi.
// SPLIT_OUT: write C as bf16 hi/lo pair; else f32.
// ---------------------------------------------------------------------------
template<bool SPLIT_OUT>
__device__ __forceinline__ void mfma_gemm(
    const u16* __restrict__ Ahg, const u16* __restrict__ Alg, long lda,
    const u16* __restrict__ BTh, const u16* __restrict__ BTl, long ldb,
    const float* __restrict__ bias,
    float* __restrict__ Cf, u16* __restrict__ Ch, u16* __restrict__ Cl,
    long ldc, int K, int row0, int col0)
{
  __shared__ short Ah[4][64][8];
  __shared__ short Al[4][64][8];
  __shared__ short Bh[8][64][8];
  __shared__ short Bl[8][64][8];

  const int tid  = threadIdx.x;
  const int wave = tid >> 6, lane = tid & 63;
  const int wm = wave & 1, wn = wave >> 1;

  f32x4 acc[2][4];
#pragma unroll
  for (int i = 0; i < 2; i++)
#pragma unroll
    for (int j = 0; j < 4; j++) acc[i][j] = (f32x4){0.f, 0.f, 0.f, 0.f};

  const int am    = tid >> 2;
  const int ako   = (tid & 3) * 8;
  const int afrag = am >> 4;
  const int alane = (am & 15) + 16 * (ako >> 3);
  const int bn     = tid >> 1;
  const int bkh    = tid & 1;
  const int bfrag  = bn >> 4;
  const int blane0 = (bn & 15) + 32 * bkh;

  const u16* ah = Ahg + (long)(row0 + am) * lda + ako;
  const u16* al = Alg + (long)(row0 + am) * lda + ako;
  const u16* bh = BTh + (long)(col0 + bn) * ldb + bkh * 16;
  const u16* bl = BTl + (long)(col0 + bn) * ldb + bkh * 16;

  for (int k0 = 0; k0 < K; k0 += 32) {
    *(short8*)&Ah[afrag][alane][0]       = *(const short8*)(ah + k0);
    *(short8*)&Al[afrag][alane][0]       = *(const short8*)(al + k0);
    *(short8*)&Bh[bfrag][blane0][0]      = *(const short8*)(bh + k0);
    *(short8*)&Bh[bfrag][blane0 + 16][0] = *(const short8*)(bh + k0 + 8);
    *(short8*)&Bl[bfrag][blane0][0]      = *(const short8*)(bl + k0);
    *(short8*)&Bl[bfrag][blane0 + 16][0] = *(const short8*)(bl + k0 + 8);
    __syncthreads();

    short8 a_h[2], a_l[2], b_h[4], b_l[4];
#pragma unroll
    for (int fm = 0; fm < 2; fm++) {
      a_h[fm] = *(short8*)&Ah[wm * 2 + fm][lane][0];
      a_l[fm] = *(short8*)&Al[wm * 2 + fm][lane][0];
    }
#pragma unroll
    for (int fn = 0; fn < 4; fn++) {
      b_h[fn] = *(short8*)&Bh[wn * 4 + fn][lane][0];
      b_l[fn] = *(short8*)&Bl[wn * 4 + fn][lane][0];
    }
#pragma unroll
    for (int fm = 0; fm < 2; fm++)
#pragma unroll
      for (int fn = 0; fn < 4; fn++) {
        acc[fm][fn] = __builtin_amdgcn_mfma_f32_16x16x32_bf16(
            a_h[fm], b_h[fn], acc[fm][fn], 0, 0, 0);
        acc[fm][fn] = __builtin_amdgcn_mfma_f32_16x16x32_bf16(
            a_h[fm], b_l[fn], acc[fm][fn], 0, 0, 0);
        acc[fm][fn] = __builtin_amdgcn_mfma_f32_16x16x32_bf16(
            a_l[fm], b_h[fn], acc[fm][fn], 0, 0, 0);
      }
    __syncthreads();
  }

  const int erow = (lane >> 4) * 4;
  const int ecol = lane & 15;
#pragma unroll
  for (int fm = 0; fm < 2; fm++)
#pragma unroll
    for (int fn = 0; fn < 4; fn++) {
      const int r0 = row0 + wm * 32 + fm * 16 + erow;
      const int cc = col0 + wn * 64 + fn * 16 + ecol;
      const float bs = bias ? bias[cc] : 0.f;
#pragma unroll
      for (int i = 0; i < 4; i++) {
        const float val = acc[fm][fn][i] + bs;
        const long idx = (long)(r0 + i) * ldc + cc;
        if constexpr (SPLIT_OUT) {
          u16 hh = f2bf(val);
          Ch[idx] = hh;
          Cl[idx] = f2bf(val - bf2f(hh));
        } else {
          Cf[idx] = val;
        }
      }
    }
}

// ---------------------------------------------------------------------------
// Weight split+transpose: W[K][N] f32 -> TH/TL[N][K] bf16 hi/lo
// ---------------------------------------------------------------------------
struct SplitTArgs {
  const float* W[4];
  u16* TH[4];
  u16* TL[4];
};

__global__ __launch_bounds__(256) void splitT_kernel(SplitTArgs s) {
  const int w = blockIdx.z;
  const float* W = s.W[w];
  u16* TH = s.TH[w];
  u16* TL = s.TL[w];
  __shared__ float tile[32][33];
  const int t = threadIdx.x;
  const int k0 = blockIdx.y * 32, n0 = blockIdx.x * 32;
  {
    const int r = t >> 3, c = (t & 7) * 4;
    float4 v = *(const float4*)(W + (long)(k0 + r) * DM + n0 + c);
    tile[r][c] = v.x; tile[r][c + 1] = v.y;
    tile[r][c + 2] = v.z; tile[r][c + 3] = v.w;
  }
  __syncthreads();
  const int n = t >> 3, k = (t & 7) * 4;
  ushort4v h, l;
#pragma unroll
  for (int i = 0; i < 4; i++) {
    float f = tile[k + i][n];
    u16 hh = f2bf(f);
    h[i] = hh;
    l[i] = f2bf(f - bf2f(hh));
  }
  *(ushort4v*)(TH + (long)(n0 + n) * DM + k0 + k) = h;
  *(ushort4v*)(TL + (long)(n0 + n) * DM + k0 + k) = l;
}

// ---------------------------------------------------------------------------
// Input split: q/k/v f32 -> bf16 hi/lo (q uses rows 1..1024, k/v rows 0..1023)
// grid (1024, BATCH, 3)
// ---------------------------------------------------------------------------
__global__ __launch_bounds__(256) void input_split_kernel(
    const float* __restrict__ q, const float* __restrict__ k,
    const float* __restrict__ v,
    u16* __restrict__ qh, u16* __restrict__ ql,
    u16* __restrict__ kh, u16* __restrict__ kl,
    u16* __restrict__ vh, u16* __restrict__ vl)
{
  const int z = blockIdx.z, b = blockIdx.y;
  const long idx = ((long)blockIdx.x * 256 + threadIdx.x) * 4;
  const float* src;
  u16 *dh, *dl;
  if (z == 0)      { src = q + (long)b * 1025 * DM + DM; dh = qh; dl = ql; }
  else if (z == 1) { src = k + (long)b * 1025 * DM;      dh = kh; dl = kl; }
  else             { src = v + (long)b * 1024 * DM;      dh = vh; dl = vl; }
  float4 x = *(const float4*)(src + idx);
  ushort4v h, l;
  float f[4] = {x.x, x.y, x.z, x.w};
#pragma unroll
  for (int i = 0; i < 4; i++) {
    u16 hh = f2bf(f[i]);
    h[i] = hh;
    l[i] = f2bf(f[i] - bf2f(hh));
  }
  const long o = (long)b * SEQ * DM + idx;
  *(ushort4v*)(dh + o) = h;
  *(ushort4v*)(dl + o) = l;
}

// ---------------------------------------------------------------------------
// Mask bit-pack: int32 {0,1} -> 1 bit/elem. grid 8192 x 256.
// ---------------------------------------------------------------------------
__global__ __launch_bounds__(256) void maskpack_kernel(
    const int* __restrict__ mask, u32* __restrict__ bits)
{
  const long g = (long)blockIdx.x * 256 + threadIdx.x;
  const int m = mask[g];
  const unsigned long long bal = __ballot(m != 0);
  const int lane = threadIdx.x & 63;
  const long wbase = (g >> 6) << 1;
  if (lane == 0)  bits[wbase]     = (u32)bal;
  if (lane == 32) bits[wbase + 1] = (u32)(bal >> 32);
}

// ---------------------------------------------------------------------------
// Fused QKV projection (MFMA, split output)
// ---------------------------------------------------------------------------
struct MfmaProjArgs {
  const u16* Ah[3];
  const u16* Al[3];
  const u16* BTh[3];
  const u16* BTl[3];
  const float* bias[3];
  u16* Ch[3];
  u16* Cl[3];
};

__global__ __launch_bounds__(256) void proj_mfma_kernel(MfmaProjArgs p) {
  const int z = blockIdx.z, sel = z >> 1, b = z & 1;
  const long off = (long)b * SEQ * DM;
  mfma_gemm<true>(p.Ah[sel] + off, p.Al[sel] + off, DM,
                  p.BTh[sel], p.BTl[sel], DM, p.bias[sel],
                  nullptr, p.Ch[sel] + off, p.Cl[sel] + off, DM, DM,
                  blockIdx.y * 64, blockIdx.x * 128);
}

__global__ __launch_bounds__(256) void out_mfma_kernel(
    const u16* __restrict__ ohsh, const u16* __restrict__ ohsl,
    const u16* __restrict__ WoTh, const u16* __restrict__ WoTl,
    const float* __restrict__ bo, float* __restrict__ out0) {
  const int b = blockIdx.z;
  const long off = (long)b * SEQ * DM;
  mfma_gemm<false>(ohsh + off, ohsl + off, DM, WoTh, WoTl, DM, bo,
                   out0 + off, nullptr, nullptr, DM, DM,
                   blockIdx.y * 64, blockIdx.x * 128);
}

// ---------------------------------------------------------------------------
// Fused attention: QBLK=64 (4 waves x 16 rows), KBLK=64, 256 threads.
// grid (16, 32) = 512 blocks -> 2 blocks/CU (49.4 KB LDS).
// Phase A: 1-term QK^T -> row sums. Phase B: 3-term QK^T -> P (normalized,
// written to att) and O += P*V (3-term). Bit-packed mask.
// ---------------------------------------------------------------------------
__global__ __launch_bounds__(256) void fused_attn_kernel(
    const u16* __restrict__ qqh, const u16* __restrict__ qql,
    const u16* __restrict__ kkh, const u16* __restrict__ kkl,
    const u16* __restrict__ vvh, const u16* __restrict__ vvl,
    const u32* __restrict__ mbits,
    float* __restrict__ attw, u16* __restrict__ ohsh, u16* __restrict__ ohsl)
{
  const int z = blockIdx.y, b = z >> 4, h = z & 15;
  const int row0 = blockIdx.x * 64;
  const long hoff = (long)b * SEQ * DM + h * DH;
  float* att = attw + (long)z * SEQ * SEQ;
  const u32* mrow = mbits + (long)b * SEQ * 32;

  __shared__ short Kh[4][2][64][8];   // 8 KB  [nf][khalf][lane][8]
  __shared__ short Kl[4][2][64][8];   // 8 KB
  __shared__ short Vh[2][4][64][8];   // 8 KB  [ks][dfrag][lane][8]
  __shared__ short Vl[2][4][64][8];   // 8 KB
  __shared__ float P[4][16][68];      // 17 KB per-wave P tile

  const int tid = threadIdx.x, w = tid >> 6, lane = tid & 63;
  const int lg = lane >> 4, lr = lane & 15;
  const int grow = row0 + 16 * w + 4 * lg;

  // ---- Q fragments (registers, whole kernel) ----
  short8 qfh[2], qfl[2];
  {
    const long qo = hoff + (long)(row0 + 16 * w + lr) * DM + 8 * lg;
#pragma unroll
    for (int kh = 0; kh < 2; kh++) {
      qfh[kh] = *(const short8*)(qqh + qo + 32 * kh);
      qfl[kh] = *(const short8*)(qql + qo + 32 * kh);
    }
  }

  // ================= Phase A: row sums (1-term) =================
  float lsum[4] = {0.f, 0.f, 0.f, 0.f};
  for (int t = 0; t < 16; t++) {
#pragma unroll
    for (int r = 0; r < 2; r++) {
      const int c = tid + 256 * r, key = c >> 3, oct = c & 7;
      *(short8*)&Kh[key >> 4][oct >> 2][(key & 15) + 16 * (oct & 3)][0] =
          *(const short8*)(kkh + hoff + (long)(t * 64 + key) * DM + 8 * oct);
    }
    __syncthreads();

    f32x4 s[4];
#pragma unroll
    for (int nf = 0; nf < 4; nf++) s[nf] = (f32x4){0.f, 0.f, 0.f, 0.f};
#pragma unroll
    for (int nf = 0; nf < 4; nf++)
#pragma unroll
      for (int kh = 0; kh < 2; kh++) {
        short8 kf = *(short8*)&Kh[nf][kh][lane][0];
        s[nf] = __builtin_amdgcn_mfma_f32_16x16x32_bf16(qfh[kh], kf, s[nf], 0, 0, 0);
      }
#pragma unroll
    for (int i = 0; i < 4; i++) {
      const uint2 mw = *(const uint2*)(mrow + (long)(grow + i) * 32 + t * 2);
      const u32 w0 = mw.x >> lr, w1 = mw.y >> lr;
#pragma unroll
      for (int nf = 0; nf < 4; nf++) {
        const u32 bit = (((nf & 2) ? w1 : w0) >> ((nf & 1) << 4)) & 1u;
        const float e = __expf(fmaxf(s[nf][i] * 0.125f, 0.f));
        lsum[i] += bit ? 0.f : e;
      }
    }
    __syncthreads();
  }
#pragma unroll
  for (int o = 1; o <= 8; o <<= 1)
#pragma unroll
    for (int i = 0; i < 4; i++)
      lsum[i] += __shfl_xor(lsum[i], o, 64);
  float linv[4];
#pragma unroll
  for (int i = 0; i < 4; i++) linv[i] = 1.f / lsum[i];

  // ================= Phase B: att write + PV =================
  f32x4 o_acc[4];
#pragma unroll
  for (int nf = 0; nf < 4; nf++) o_acc[nf] = (f32x4){0.f, 0.f, 0.f, 0.f};

  for (int t = 0; t < 16; t++) {
#pragma unroll
    for (int r = 0; r < 2; r++) {
      const int c = tid + 256 * r, key = c >> 3, oct = c & 7;
      const long gk = hoff + (long)(t * 64 + key) * DM + 8 * oct;
      const int nf = key >> 4, khf = oct >> 2;
      const int ln = (key & 15) + 16 * (oct & 3);
      *(short8*)&Kh[nf][khf][ln][0] = *(const short8*)(kkh + gk);
      *(short8*)&Kl[nf][khf][ln][0] = *(const short8*)(kkl + gk);
    }
#pragma unroll
    for (int r = 0; r < 2; r++) {
      const int c = tid + 256 * r, key = c >> 3, oct = c & 7, d0 = oct * 8;
      const long gv = hoff + (long)(t * 64 + key) * DM + d0;
      short8 vh8 = *(const short8*)(vvh + gv);
      short8 vl8 = *(const short8*)(vvl + gv);
      const int ks = key >> 5, g2 = (key & 31) >> 3, j = key & 7;
#pragma unroll
      for (int e = 0; e < 8; e++) {
        const int d = d0 + e;
        Vh[ks][d >> 4][(d & 15) + 16 * g2][j] = vh8[e];
        Vl[ks][d >> 4][(d & 15) + 16 * g2][j] = vl8[e];
      }
    }
    __syncthreads();

    f32x4 s[4];
#pragma unroll
    for (int nf = 0; nf < 4; nf++) s[nf] = (f32x4){0.f, 0.f, 0.f, 0.f};
#pragma unroll
    for (int nf = 0; nf < 4; nf++)
#pragma unroll
      for (int kh = 0; kh < 2; kh++) {
        short8 kfh = *(short8*)&Kh[nf][kh][lane][0];
        short8 kfl = *(short8*)&Kl[nf][kh][lane][0];
        s[nf] = __builtin_amdgcn_mfma_f32_16x16x32_bf16(qfh[kh], kfh, s[nf], 0, 0, 0);
        s[nf] = __builtin_amdgcn_mfma_f32_16x16x32_bf16(qfh[kh], kfl, s[nf], 0, 0, 0);
        s[nf] = __builtin_amdgcn_mfma_f32_16x16x32_bf16(qfl[kh], kfh, s[nf], 0, 0, 0);
      }

#pragma unroll
    for (int i = 0; i < 4; i++) {
      const uint2 mw = *(const uint2*)(mrow + (long)(grow + i) * 32 + t * 2);
      const u32 w0 = mw.x >> lr, w1 = mw.y >> lr;
#pragma unroll
      for (int nf = 0; nf < 4; nf++) {
        const u32 bit = (((nf & 2) ? w1 : w0) >> ((nf & 1) << 4)) & 1u;
        const float e = __expf(fmaxf(s[nf][i] * 0.125f, 0.f)) * linv[i];
        P[w][4 * lg + i][16 * nf + lr] = bit ? 0.f : e;
      }
    }

    // ---- P A-frags (same-wave LDS round trip, in-order per wave) ----
    short8 pah[2], pal[2];
#pragma unroll
    for (int ks = 0; ks < 2; ks++) {
      float4 x = *(float4*)&P[w][lr][32 * ks + 8 * lg];
      float4 y = *(float4*)&P[w][lr][32 * ks + 8 * lg + 4];
      split8(x, y, pah[ks], pal[ks]);
    }

#pragma unroll
    for (int ks = 0; ks < 2; ks++)
#pragma unroll
      for (int nf = 0; nf < 4; nf++) {
        short8 vfh = *(short8*)&Vh[ks][nf][lane][0];
        short8 vfl = *(short8*)&Vl[ks][nf][lane][0];
        o_acc[nf] = __builtin_amdgcn_mfma_f32_16x16x32_bf16(pah[ks], vfh, o_acc[nf], 0, 0, 0);
        o_acc[nf] = __builtin_amdgcn_mfma_f32_16x16x32_bf16(pah[ks], vfl, o_acc[nf], 0, 0, 0);
        o_acc[nf] = __builtin_amdgcn_mfma_f32_16x16x32_bf16(pal[ks], vfh, o_acc[nf], 0, 0, 0);
      }

    // ---- att write (4 rows x 256B per instr) ----
#pragma unroll
    for (int rr = 0; rr < 4; rr++) {
      const int row = (lane >> 4) + 4 * rr;
      float4 pv = *(float4*)&P[w][row][4 * (lane & 15)];
      *(float4*)(att + (long)(row0 + 16 * w + row) * SEQ + t * 64 + 4 * (lane & 15)) = pv;
    }
    __syncthreads();
  }

  // ---- O epilogue: split to bf16 hi/lo for the out GEMM ----
#pragma unroll
  for (int nf = 0; nf < 4; nf++)
#pragma unroll
    for (int i = 0; i < 4; i++) {
      const float o = o_acc[nf][i];
      const u16 hh = f2bf(o);
      const long idx = (long)b * SEQ * DM + (long)(grow + i) * DM + h * DH + 16 * nf + lr;
      ohsh[idx] = hh;
      ohsl[idx] = f2bf(o - bf2f(hh));
    }
}

// ---------------------------------------------------------------------------
extern "C" void kernel_launch(void* const* d_in, const int* in_sizes, int n_in,
                              void* d_out, int out_size, void* d_ws, size_t ws_size,
                              hipStream_t stream)
{
  const float* v    = (const float*)d_in[0];
  const float* k    = (const float*)d_in[1];
  const float* q    = (const float*)d_in[2];
  const int*   mask = (const int*)  d_in[3];
  const float* Wq   = (const float*)d_in[4];
  const float* bq   = (const float*)d_in[5];
  const float* Wk   = (const float*)d_in[6];
  const float* bk   = (const float*)d_in[7];
  const float* Wv   = (const float*)d_in[8];
  const float* bv   = (const float*)d_in[9];
  const float* Wo   = (const float*)d_in[10];
  const float* bo   = (const float*)d_in[11];

  const long NE  = (long)SEQ * DM;       // 1M
  const long BNE = (long)BATCH * NE;     // 2M

  // ---- workspace (36.25 MB): all bf16 hi/lo activation buffers + mask bits
  u16* qqh  = (u16*)d_ws;
  u16* qql  = qqh  + BNE;
  u16* kkh  = qql  + BNE;
  u16* kkl  = kkh  + BNE;
  u16* vvh  = kkl  + BNE;
  u16* vvl  = vvh  + BNE;
  u16* ohsh = vvl  + BNE;
  u16* ohsl = ohsh + BNE;
  u16* WoTh = ohsl + BNE;
  u16* WoTl = WoTh + NE;
  u32* mbits = (u32*)(WoTl + NE);        // 65536 words

  float* out0 = (float*)d_out;
  float* attw = out0 + BNE;

  // ---- stash in att-region tail (36 MB; consumed before fused overwrites)
  u16* sbase = (u16*)(attw + (long)BATCH * NH * SEQ * SEQ) - 18L * NE;
  u16* WqTh = sbase;
  u16* WqTl = WqTh + NE;
  u16* WkTh = WqTl + NE;
  u16* WkTl = WkTh + NE;
  u16* WvTh = WkTl + NE;
  u16* WvTl = WvTh + NE;
  u16* qinh = WvTl + NE;
  u16* qinl = qinh + BNE;
  u16* kinh = qinl + BNE;
  u16* kinl = kinh + BNE;
  u16* vinh = kinl + BNE;
  u16* vinl = vinh + BNE;

  dim3 blk(256);

  SplitTArgs st;
  st.W[0] = Wq; st.W[1] = Wk; st.W[2] = Wv; st.W[3] = Wo;
  st.TH[0] = WqTh; st.TH[1] = WkTh; st.TH[2] = WvTh; st.TH[3] = WoTh;
  st.TL[0] = WqTl; st.TL[1] = WkTl; st.TL[2] = WvTl; st.TL[3] = WoTl;
  hipLaunchKernelGGL(splitT_kernel, dim3(32, 32, 4), blk, 0, stream, st);

  hipLaunchKernelGGL(input_split_kernel, dim3(1024, BATCH, 3), blk, 0, stream,
                     q, k, v, qinh, qinl, kinh, kinl, vinh, vinl);

  hipLaunchKernelGGL(maskpack_kernel, dim3(8192), blk, 0, stream, mask, mbits);

  MfmaProjArgs p;
  p.Ah[0] = qinh; p.Al[0] = qinl;
  p.Ah[1] = kinh; p.Al[1] = kinl;
  p.Ah[2] = vinh; p.Al[2] = vinl;
  p.BTh[0] = WqTh; p.BTl[0] = WqTl;
  p.BTh[1] = WkTh; p.BTl[1] = WkTl;
  p.BTh[2] = WvTh; p.BTl[2] = WvTl;
  p.bias[0] = bq; p.bias[1] = bk; p.bias[2] = bv;
  p.Ch[0] = qqh; p.Cl[0] = qql;
  p.Ch[1] = kkh; p.Cl[1] = kkl;
  p.Ch[2] = vvh; p.Cl[2] = vvl;
  hipLaunchKernelGGL(proj_mfma_kernel, dim3(8, 16, 6), blk, 0, stream, p);

  hipLaunchKernelGGL(fused_attn_kernel, dim3(16, BATCH * NH), blk, 0, stream,
                     qqh, qql, kkh, kkl, vvh, vvl, mbits, attw, ohsh, ohsl);

  hipLaunchKernelGGL(out_mfma_kernel, dim3(8, 16, 2), blk, 0, stream,
                     ohsh, ohsl, WoTh, WoTl, bo, out0);
}